// Round 4
// baseline (176.720 us; speedup 1.0000x reference)
//
#include <hip/hip_runtime.h>
#include <hip/hip_bf16.h>

// Dims fixed by setup_inputs(): b=8, t=64, s=512, qu=vu=d=512.
#define B_  8
#define T_  64
#define S_  512
#define D_  512

#define QN (512 * 512)      // q partial elements (B*T x D)
#define KN (4096 * 512)     // k partial elements (B*S x D)
#define SN (B_ * T_ * S_)   // scores elements

#define TLOG2E 2.8853900817779268f   // 2*log2(e)
#define LOG2E  1.4426950408889634f

// ---------------------------------------------------------------------------
// Fused projection GEMMs, split-K=2 for BOTH (uniform K-depth 256/block).
// Epilogue pre-scales by 2*log2(e); q split 0 additionally folds (b1+b2).
// Consumers sum the two partials. Softmax shift-invariance means scores can
// drop the csum constant entirely.
//   blocks 0..1023   : k-GEMM (value@W2): b=x&7, r=x>>3: tn=r&7,
//                      tml=(r>>3)&7, split=r>>6; tm=b*8+tml.
//   blocks 1024..1151: q-GEMM (query@W1): r=x-1024: tm=r&7, tn=(r>>3)&7,
//                      split=r>>6.
// ---------------------------------------------------------------------------
#define BM 64
#define BN 64
#define BK 32

__global__ __launch_bounds__(256) void proj_gemm(
    const float* __restrict__ query, const float* __restrict__ value,
    const float* __restrict__ W1, const float* __restrict__ W2,
    const float* __restrict__ b1, const float* __restrict__ b2,
    float* __restrict__ qpart, float* __restrict__ kpart)
{
    __shared__ float As[BK][BM + 4];
    __shared__ float Bs[BK][BN + 4];

    const int x = blockIdx.x;
    const float* A; const float* Bw; float* C;
    int kbeg, tm, tn;
    bool add_bias;
    if (x < 1024) {
        int b = x & 7;
        int r = x >> 3;
        tn = r & 7;
        int tml = (r >> 3) & 7;
        int split = r >> 6;          // 0..1
        tm = b * 8 + tml;
        kbeg = split * 256;
        A = value; Bw = W2;
        C = kpart + (size_t)split * KN;
        add_bias = false;
    } else {
        int r = x - 1024;
        tm = r & 7;
        tn = (r >> 3) & 7;
        int split = r >> 6;          // 0..1
        kbeg = split * 256;
        A = query; Bw = W1;
        C = qpart + (size_t)split * QN;
        add_bias = (split == 0);
    }
    const int kend = kbeg + 256;

    const int tid = threadIdx.x;
    const int tx = tid & 15, ty = tid >> 4;

    float acc[4][4] = {};

    const int a_row = tid >> 2;          // 0..63
    const int a_k8  = (tid & 3) * 8;     // 0,8,16,24
    const int b_k   = tid >> 4;          // 0..15
    const int b_c4  = (tid & 15) * 4;

    const float* Ablk = A + (size_t)(tm * BM) * D_;
    const float* Bblk = Bw + tn * BN;

    for (int k0 = kbeg; k0 < kend; k0 += BK) {
        float4 av0 = *(const float4*)(Ablk + (size_t)a_row * D_ + k0 + a_k8);
        float4 av1 = *(const float4*)(Ablk + (size_t)a_row * D_ + k0 + a_k8 + 4);
        float4 bv0 = *(const float4*)(Bblk + (size_t)(k0 + b_k) * D_ + b_c4);
        float4 bv1 = *(const float4*)(Bblk + (size_t)(k0 + b_k + 16) * D_ + b_c4);
        As[a_k8 + 0][a_row] = av0.x;
        As[a_k8 + 1][a_row] = av0.y;
        As[a_k8 + 2][a_row] = av0.z;
        As[a_k8 + 3][a_row] = av0.w;
        As[a_k8 + 4][a_row] = av1.x;
        As[a_k8 + 5][a_row] = av1.y;
        As[a_k8 + 6][a_row] = av1.z;
        As[a_k8 + 7][a_row] = av1.w;
        *(float4*)&Bs[b_k][b_c4] = bv0;
        *(float4*)&Bs[b_k + 16][b_c4] = bv1;
        __syncthreads();
#pragma unroll
        for (int kk = 0; kk < BK; ++kk) {
            float4 a = *(const float4*)&As[kk][ty * 4];
            float4 b = *(const float4*)&Bs[kk][tx * 4];
            acc[0][0] = fmaf(a.x, b.x, acc[0][0]);
            acc[0][1] = fmaf(a.x, b.y, acc[0][1]);
            acc[0][2] = fmaf(a.x, b.z, acc[0][2]);
            acc[0][3] = fmaf(a.x, b.w, acc[0][3]);
            acc[1][0] = fmaf(a.y, b.x, acc[1][0]);
            acc[1][1] = fmaf(a.y, b.y, acc[1][1]);
            acc[1][2] = fmaf(a.y, b.z, acc[1][2]);
            acc[1][3] = fmaf(a.y, b.w, acc[1][3]);
            acc[2][0] = fmaf(a.z, b.x, acc[2][0]);
            acc[2][1] = fmaf(a.z, b.y, acc[2][1]);
            acc[2][2] = fmaf(a.z, b.z, acc[2][2]);
            acc[2][3] = fmaf(a.z, b.w, acc[2][3]);
            acc[3][0] = fmaf(a.w, b.x, acc[3][0]);
            acc[3][1] = fmaf(a.w, b.y, acc[3][1]);
            acc[3][2] = fmaf(a.w, b.z, acc[3][2]);
            acc[3][3] = fmaf(a.w, b.w, acc[3][3]);
        }
        __syncthreads();
    }

    const int row0 = tm * BM + ty * 4;
    const int col0 = tn * BN + tx * 4;
    float4 bi; bi.x = 0.f; bi.y = 0.f; bi.z = 0.f; bi.w = 0.f;
    if (add_bias) {
        float4 u = *(const float4*)(b1 + col0);
        float4 v = *(const float4*)(b2 + col0);
        bi.x = u.x + v.x; bi.y = u.y + v.y;
        bi.z = u.z + v.z; bi.w = u.w + v.w;
    }
#pragma unroll
    for (int i = 0; i < 4; ++i) {
        float4 o;
        o.x = (acc[i][0] + bi.x) * TLOG2E;
        o.y = (acc[i][1] + bi.y) * TLOG2E;
        o.z = (acc[i][2] + bi.z) * TLOG2E;
        o.w = (acc[i][3] + bi.w) * TLOG2E;
        *(float4*)(C + (size_t)(row0 + i) * D_ + col0) = o;
    }
}

// ---------------------------------------------------------------------------
// Transposed scores: each THREAD owns one (t,s) score partial over a d-half.
// Stored value = -2 * sum_d c_d * rcp(exp2(q'+k')+1)  (csum dropped —
// softmax is shift-invariant; masked lanes store -5e8 so part0+part1=-1e9).
// Block = 256 thr = 16 t x 16 s; LDS tiles k/q (pad 132) + scale, d-chunk 128.
// Grid 2048: blk = ((((tg*32+sg)*2)+dh) << 3) | b   (b low bits = XCD pin).
// No cross-lane ops at all.
// ---------------------------------------------------------------------------
__global__ __launch_bounds__(256) void scores_t(
    const float* __restrict__ qpart, const float* __restrict__ kpart,
    const int*   __restrict__ mask,  const float* __restrict__ scale,
    float* __restrict__ sparts)
{
    const int blk = blockIdx.x;
    const int b  = blk & 7;
    int r = blk >> 3;                 // 0..255
    const int dh = r & 1;
    r >>= 1;                          // 0..127
    const int sg = r & 31;
    const int tg = r >> 5;            // 0..3
    const int t0 = tg * 16, s0 = sg * 16;
    const int dbase = dh * 256;

    __shared__ float kT[16][132];
    __shared__ float qT[16][132];
    __shared__ float cS[128];

    const int tid  = threadIdx.x;
    const int srow = tid >> 4;        // staging row 0..15
    const int scol = (tid & 15) * 8;  // staging col 0..120

    const int t_l = tid >> 4;         // compute: own t (0..15)
    const int s_l = tid & 15;         // compute: own s (0..15)

    const int m = mask[b * S_ + s0 + s_l];

    float p0 = 0.f, p1 = 0.f;

#pragma unroll
    for (int c = 0; c < 2; ++c) {
        const int dc = dbase + c * 128;
        // stage k-tile: sum of 2 split-K partials (already *2log2e)
        {
            const float* kp = kpart + (size_t)(b * S_ + s0 + srow) * D_ + dc + scol;
            float4 x0 = *(const float4*)(kp);
            float4 x1 = *(const float4*)(kp + 4);
            float4 y0 = *(const float4*)(kp + KN);
            float4 y1 = *(const float4*)(kp + KN + 4);
            float4 o0, o1;
            o0.x = x0.x + y0.x; o0.y = x0.y + y0.y;
            o0.z = x0.z + y0.z; o0.w = x0.w + y0.w;
            o1.x = x1.x + y1.x; o1.y = x1.y + y1.y;
            o1.z = x1.z + y1.z; o1.w = x1.w + y1.w;
            *(float4*)&kT[srow][scol]     = o0;
            *(float4*)&kT[srow][scol + 4] = o1;
        }
        // stage q-tile: sum of 2 split-K partials (bias folded in part 0)
        {
            const float* qp = qpart + (size_t)(b * T_ + t0 + srow) * D_ + dc + scol;
            float4 x0 = *(const float4*)(qp);
            float4 x1 = *(const float4*)(qp + 4);
            float4 y0 = *(const float4*)(qp + QN);
            float4 y1 = *(const float4*)(qp + QN + 4);
            float4 o0, o1;
            o0.x = x0.x + y0.x; o0.y = x0.y + y0.y;
            o0.z = x0.z + y0.z; o0.w = x0.w + y0.w;
            o1.x = x1.x + y1.x; o1.y = x1.y + y1.y;
            o1.z = x1.z + y1.z; o1.w = x1.w + y1.w;
            *(float4*)&qT[srow][scol]     = o0;
            *(float4*)&qT[srow][scol + 4] = o1;
        }
        if (tid < 32) {
            *(float4*)&cS[tid * 4] = *(const float4*)(scale + dc + tid * 4);
        }
        __syncthreads();

#pragma unroll
        for (int j = 0; j < 32; ++j) {
            float4 k4 = *(const float4*)&kT[s_l][j * 4];
            float4 q4 = *(const float4*)&qT[t_l][j * 4];
            float4 c4 = *(const float4*)&cS[j * 4];
            float e0 = __builtin_amdgcn_exp2f(q4.x + k4.x);
            float e1 = __builtin_amdgcn_exp2f(q4.y + k4.y);
            float e2 = __builtin_amdgcn_exp2f(q4.z + k4.z);
            float e3 = __builtin_amdgcn_exp2f(q4.w + k4.w);
            float r0 = __builtin_amdgcn_rcpf(e0 + 1.0f);
            float r1 = __builtin_amdgcn_rcpf(e1 + 1.0f);
            float r2 = __builtin_amdgcn_rcpf(e2 + 1.0f);
            float r3 = __builtin_amdgcn_rcpf(e3 + 1.0f);
            p0 = fmaf(c4.x, r0, p0);
            p1 = fmaf(c4.y, r1, p1);
            p0 = fmaf(c4.z, r2, p0);
            p1 = fmaf(c4.w, r3, p1);
        }
        __syncthreads();
    }

    const float p = p0 + p1;
    const float out = m ? (-2.0f * p) : -5e8f;
    sparts[(size_t)dh * SN + (size_t)(b * T_ + t0 + t_l) * S_ + s0 + s_l] = out;
}

// ---------------------------------------------------------------------------
// Softmax + context. Grid 1024: blk = ((tp*4 + vc) << 3) | b.
// Softmax sums the two d-half score partials. Context: float4 value loads,
// 8 s-streams of 64 x 32 v4-slots; LDS partial combine.
// ---------------------------------------------------------------------------
__global__ __launch_bounds__(256) void softmax_ctx(
    const float* __restrict__ sparts, const float* __restrict__ value,
    float* __restrict__ ctx, float* __restrict__ attn)
{
    const int blk = blockIdx.x;
    const int b = blk & 7;
    int r = blk >> 3;
    const int vc = r & 3;        // v-chunk of 128
    const int tp = r >> 2;       // 0..31
    const int t0 = tp * 2, t1 = t0 + 1;
    const size_t row0 = (size_t)(b * T_ + t0) * S_;
    const size_t row1 = row0 + S_;

    const int tid  = threadIdx.x;
    const int lane = tid & 63;
    const int wid  = tid >> 6;

    __shared__ float2 wp[S_];          // (w_t0, w_t1) per s
    __shared__ float4 part[2][8][32];  // [t][s-stream][v4]
    __shared__ float2 red2[8];

    const int sa = tid, sb = tid + 256;
    float2 xa, xb;
    xa.x = sparts[row0 + sa] + sparts[SN + row0 + sa];
    xa.y = sparts[row1 + sa] + sparts[SN + row1 + sa];
    xb.x = sparts[row0 + sb] + sparts[SN + row0 + sb];
    xb.y = sparts[row1 + sb] + sparts[SN + row1 + sb];

    float2 m2; m2.x = fmaxf(xa.x, xb.x); m2.y = fmaxf(xa.y, xb.y);
#pragma unroll
    for (int off = 32; off >= 1; off >>= 1) {
        m2.x = fmaxf(m2.x, __shfl_xor(m2.x, off));
        m2.y = fmaxf(m2.y, __shfl_xor(m2.y, off));
    }
    if (lane == 0) red2[wid] = m2;
    __syncthreads();
    {
        float2 r0 = red2[0], r1 = red2[1], r2 = red2[2], r3 = red2[3];
        m2.x = fmaxf(fmaxf(r0.x, r1.x), fmaxf(r2.x, r3.x));
        m2.y = fmaxf(fmaxf(r0.y, r1.y), fmaxf(r2.y, r3.y));
    }

    float2 ea, eb;
    ea.x = __builtin_amdgcn_exp2f((xa.x - m2.x) * LOG2E);
    ea.y = __builtin_amdgcn_exp2f((xa.y - m2.y) * LOG2E);
    eb.x = __builtin_amdgcn_exp2f((xb.x - m2.x) * LOG2E);
    eb.y = __builtin_amdgcn_exp2f((xb.y - m2.y) * LOG2E);

    float2 s2; s2.x = ea.x + eb.x; s2.y = ea.y + eb.y;
#pragma unroll
    for (int off = 32; off >= 1; off >>= 1) {
        s2.x += __shfl_xor(s2.x, off);
        s2.y += __shfl_xor(s2.y, off);
    }
    if (lane == 0) red2[4 + wid] = s2;
    __syncthreads();
    {
        float2 r0 = red2[4], r1 = red2[5], r2 = red2[6], r3 = red2[7];
        s2.x = (r0.x + r1.x) + (r2.x + r3.x);
        s2.y = (r0.y + r1.y) + (r2.y + r3.y);
    }
    const float inv0 = 1.0f / s2.x, inv1 = 1.0f / s2.y;

    float wa0 = ea.x * inv0, wb0 = eb.x * inv0;   // t0 at s=sa, sb
    float wa1 = ea.y * inv1, wb1 = eb.y * inv1;   // t1

    float2 wsa; wsa.x = wa0; wsa.y = wa1;
    float2 wsb; wsb.x = wb0; wsb.y = wb1;
    wp[sa] = wsa;
    wp[sb] = wsb;
    if (vc == 0) {
        attn[row0 + sa] = wa0; attn[row0 + sb] = wb0;
        attn[row1 + sa] = wa1; attn[row1 + sb] = wb1;
    }
    __syncthreads();

    // context: 8 s-streams (wid*2 + lane>>5), 32 v4-slots, float4 loads.
    const int ssub = wid * 2 + (lane >> 5);   // 0..7, owns s in [ssub*64, +64)
    const int v4   = lane & 31;
    const int v    = vc * 128 + v4 * 4;
    const float* vb = value + ((size_t)(b * S_) + ssub * 64) * D_ + v;
    float4 a0; a0.x = 0.f; a0.y = 0.f; a0.z = 0.f; a0.w = 0.f;
    float4 a1 = a0;
#pragma unroll 4
    for (int i = 0; i < 64; ++i) {
        float4 vv = *(const float4*)(vb + (size_t)i * D_);
        float2 w2 = wp[ssub * 64 + i];
        a0.x = fmaf(w2.x, vv.x, a0.x);
        a0.y = fmaf(w2.x, vv.y, a0.y);
        a0.z = fmaf(w2.x, vv.z, a0.z);
        a0.w = fmaf(w2.x, vv.w, a0.w);
        a1.x = fmaf(w2.y, vv.x, a1.x);
        a1.y = fmaf(w2.y, vv.y, a1.y);
        a1.z = fmaf(w2.y, vv.z, a1.z);
        a1.w = fmaf(w2.y, vv.w, a1.w);
    }
    part[0][ssub][v4] = a0;
    part[1][ssub][v4] = a1;
    __syncthreads();
    if (tid < 64) {
        const int ts = tid >> 5, w4 = tid & 31;
        float4 s0 = part[ts][0][w4], s1 = part[ts][1][w4];
        float4 s2v = part[ts][2][w4], s3 = part[ts][3][w4];
        float4 s4 = part[ts][4][w4], s5 = part[ts][5][w4];
        float4 s6 = part[ts][6][w4], s7 = part[ts][7][w4];
        float4 o;
        o.x = ((s0.x + s1.x) + (s2v.x + s3.x)) + ((s4.x + s5.x) + (s6.x + s7.x));
        o.y = ((s0.y + s1.y) + (s2v.y + s3.y)) + ((s4.y + s5.y) + (s6.y + s7.y));
        o.z = ((s0.z + s1.z) + (s2v.z + s3.z)) + ((s4.z + s5.z) + (s6.z + s7.z));
        o.w = ((s0.w + s1.w) + (s2v.w + s3.w)) + ((s4.w + s5.w) + (s6.w + s7.w));
        *(float4*)(ctx + (size_t)(b * T_ + t0 + ts) * D_ + vc * 128 + w4 * 4) = o;
    }
}

extern "C" void kernel_launch(void* const* d_in, const int* in_sizes, int n_in,
                              void* d_out, int out_size, void* d_ws, size_t ws_size,
                              hipStream_t stream) {
    const float* query = (const float*)d_in[0];
    const float* value = (const float*)d_in[1];
    const int*   mask  = (const int*)  d_in[2];
    const float* W1w   = (const float*)d_in[3];
    const float* W1b   = (const float*)d_in[4];
    const float* W2w   = (const float*)d_in[5];
    const float* W2b   = (const float*)d_in[6];
    const float* scale = (const float*)d_in[7];

    float* ctx  = (float*)d_out;
    float* attn = (float*)d_out + (size_t)B_ * T_ * D_;

    float* qpart = (float*)d_ws;              // 2 * QN  (2 MB)
    float* kpart = qpart + 2 * (size_t)QN;    // 2 * KN  (16 MB)
    float* spart = kpart + 2 * (size_t)KN;    // 2 * SN  (2 MB)

    proj_gemm<<<1152, 256, 0, stream>>>(query, value, W1w, W2w, W1b, W2b,
                                        qpart, kpart);
    scores_t<<<2048, 256, 0, stream>>>(qpart, kpart, mask, scale, spart);
    softmax_ctx<<<1024, 256, 0, stream>>>(spart, value, ctx, attn);
}

// Round 5
// 135.409 us; speedup vs baseline: 1.3051x; 1.3051x over previous
//
#include <hip/hip_runtime.h>
#include <hip/hip_bf16.h>

// Dims fixed by setup_inputs(): b=8, t=64, s=512, qu=vu=d=512.
#define B_  8
#define T_  64
#define S_  512
#define D_  512

#define QN (512 * 512)      // qproj elements (B*T x D)
#define KN (4096 * 512)     // kproj elements (B*S x D)
#define SN (B_ * T_ * S_)   // scores elements

#define TLOG2E 2.8853900817779268f   // 2*log2(e)
#define LOG2E  1.4426950408889634f

typedef __attribute__((ext_vector_type(8))) short bf16x8;
typedef __attribute__((ext_vector_type(4))) float f32x4;

__device__ __forceinline__ unsigned short f2bf(float f) {
    unsigned int u = __float_as_uint(f);
    return (unsigned short)((u + 0x7FFFu + ((u >> 16) & 1u)) >> 16);  // RNE
}
__device__ __forceinline__ unsigned int pk2(float a, float b) {
    return (unsigned int)f2bf(a) | ((unsigned int)f2bf(b) << 16);
}

// ---------------------------------------------------------------------------
// Pack: query/value -> bf16 (same layout); W1/W2 -> bf16 TRANSPOSED
// (Wt[n][k]) so GEMM B-fragments are contiguous. Grid 1408 blocks:
//   [0,1024)   vb   (value, 2M elems, 8/thread)
//   [1024,1152) qb  (query, 256K)
//   [1152,1280) w1t (transpose)
//   [1280,1408) w2t (transpose)
// ---------------------------------------------------------------------------
__global__ __launch_bounds__(256) void pack_bf16(
    const float* __restrict__ query, const float* __restrict__ value,
    const float* __restrict__ W1, const float* __restrict__ W2,
    unsigned short* __restrict__ qb, unsigned short* __restrict__ vb,
    unsigned short* __restrict__ w1t, unsigned short* __restrict__ w2t)
{
    const int blk = blockIdx.x;
    const int tid = threadIdx.x;
    if (blk < 1152) {
        const float* src; unsigned short* dst; int lb;
        if (blk < 1024) { src = value; dst = vb; lb = blk; }
        else            { src = query; dst = qb; lb = blk - 1024; }
        size_t o = (size_t)lb * 2048 + tid * 8;
        float4 x = *(const float4*)(src + o);
        float4 y = *(const float4*)(src + o + 4);
        uint4 p;
        p.x = pk2(x.x, x.y); p.y = pk2(x.z, x.w);
        p.z = pk2(y.x, y.y); p.w = pk2(y.z, y.w);
        *(uint4*)(dst + o) = p;
    } else {
        const float* W; unsigned short* Wt; int lb;
        if (blk < 1280) { W = W1; Wt = w1t; lb = blk - 1152; }
        else            { W = W2; Wt = w2t; lb = blk - 1280; }
        size_t o = (size_t)lb * 2048 + tid * 8;
        const int n  = (int)(o >> 9);
        const int k0 = (int)(o & 511);
        uint4 p;
        p.x = pk2(W[(size_t)(k0 + 0) * 512 + n], W[(size_t)(k0 + 1) * 512 + n]);
        p.y = pk2(W[(size_t)(k0 + 2) * 512 + n], W[(size_t)(k0 + 3) * 512 + n]);
        p.z = pk2(W[(size_t)(k0 + 4) * 512 + n], W[(size_t)(k0 + 5) * 512 + n]);
        p.w = pk2(W[(size_t)(k0 + 6) * 512 + n], W[(size_t)(k0 + 7) * 512 + n]);
        *(uint4*)(Wt + o) = p;
    }
}

// ---------------------------------------------------------------------------
// bf16 MFMA projection GEMM. Block = 64x64 tile, 4 waves, each wave 2x2 of
// 16x16x32 mfma. Epilogue: *TLOG2E; q-GEMM adds (b1+b2) first.
//   blocks [0,512):   kproj = vb @ W2   (tm = x>>3, tn = x&7  -> tn pins XCD)
//   blocks [512,576): qproj = qb @ W1   (r = x-512: tm = r>>3, tn = r&7)
// LDS rows padded to 40 ushorts (80 B): frag-read bank quad = (5*m+fq)%8,
// distinct for m mod 8 -> 2-way max (free).
// ---------------------------------------------------------------------------
__global__ __launch_bounds__(256) void mfma_gemm(
    const unsigned short* __restrict__ qb, const unsigned short* __restrict__ vb,
    const unsigned short* __restrict__ w1t, const unsigned short* __restrict__ w2t,
    const float* __restrict__ b1, const float* __restrict__ b2,
    float* __restrict__ qproj, float* __restrict__ kproj)
{
    __shared__ __align__(16) unsigned short Ab[64][40];
    __shared__ __align__(16) unsigned short Bb[64][40];

    const int x = blockIdx.x;
    const unsigned short *A, *Bt;
    float* C;
    int tm, tn;
    bool isq;
    if (x < 512) {
        tm = x >> 3; tn = x & 7;
        A = vb; Bt = w2t; C = kproj; isq = false;
    } else {
        int r = x - 512;
        tm = r >> 3; tn = r & 7;
        A = qb; Bt = w1t; C = qproj; isq = true;
    }

    const int tid  = threadIdx.x;
    const int lane = tid & 63;
    const int wid  = tid >> 6;
    const int wm = (wid & 1) * 32, wn = (wid >> 1) * 32;
    const int fm = lane & 15, fq = lane >> 4;

    f32x4 acc00 = {0.f, 0.f, 0.f, 0.f};
    f32x4 acc01 = acc00, acc10 = acc00, acc11 = acc00;

    const int ar = tid >> 2;           // staging row 0..63
    const int ac = (tid & 3) * 8;      // staging col (ushorts) 0,8,16,24
    const unsigned short* Ag = A  + (size_t)(tm * 64 + ar) * 512 + ac;
    const unsigned short* Bg = Bt + (size_t)(tn * 64 + ar) * 512 + ac;

    for (int k0 = 0; k0 < 512; k0 += 32) {
        *(uint4*)&Ab[ar][ac] = *(const uint4*)(Ag + k0);
        *(uint4*)&Bb[ar][ac] = *(const uint4*)(Bg + k0);
        __syncthreads();
        bf16x8 a0 = *(const bf16x8*)&Ab[wm + fm][fq * 8];
        bf16x8 a1 = *(const bf16x8*)&Ab[wm + 16 + fm][fq * 8];
        bf16x8 b0 = *(const bf16x8*)&Bb[wn + fm][fq * 8];
        bf16x8 b1v = *(const bf16x8*)&Bb[wn + 16 + fm][fq * 8];
        acc00 = __builtin_amdgcn_mfma_f32_16x16x32_bf16(a0, b0,  acc00, 0, 0, 0);
        acc01 = __builtin_amdgcn_mfma_f32_16x16x32_bf16(a0, b1v, acc01, 0, 0, 0);
        acc10 = __builtin_amdgcn_mfma_f32_16x16x32_bf16(a1, b0,  acc10, 0, 0, 0);
        acc11 = __builtin_amdgcn_mfma_f32_16x16x32_bf16(a1, b1v, acc11, 0, 0, 0);
        __syncthreads();
    }

    // C/D layout (m89-verified): col = lane&15, row = fq*4 + reg.
    const int n0 = tn * 64 + wn + fm;
    const int n1 = n0 + 16;
    float bias0 = 0.f, bias1 = 0.f;
    if (isq) {
        bias0 = b1[n0] + b2[n0];
        bias1 = b1[n1] + b2[n1];
    }
    const int m0 = tm * 64 + wm + fq * 4;
#pragma unroll
    for (int r = 0; r < 4; ++r) {
        C[(size_t)(m0 + r) * 512 + n0]      = (acc00[r] + bias0) * TLOG2E;
        C[(size_t)(m0 + r) * 512 + n1]      = (acc01[r] + bias1) * TLOG2E;
        C[(size_t)(m0 + 16 + r) * 512 + n0] = (acc10[r] + bias0) * TLOG2E;
        C[(size_t)(m0 + 16 + r) * 512 + n1] = (acc11[r] + bias1) * TLOG2E;
    }
}

// ---------------------------------------------------------------------------
// Transposed scores, fixed: thread owns one (t,s) over a d-half. Stored value
// = -2*sum_d c_d*rcp(exp2(q'+k')+1) (csum dropped; softmax shift-invariant).
// Masked lanes: -5e8 per half (sum = -1e9). q',k' pre-scaled by 2log2e +
// bias-folded in GEMM. Staging: 32-lane rows (512B coalesced global,
// lane->quad = lane%8 conflict-free LDS). __launch_bounds__(256,4) caps
// VGPR at 128 (R4 bug: 208 VGPR -> 10.9% occupancy).
// Grid 2048: blk = ((((tg*32+sg)*2)+dh) << 3) | b.
// ---------------------------------------------------------------------------
__global__ __launch_bounds__(256, 4) void scores_t(
    const float* __restrict__ qproj, const float* __restrict__ kproj,
    const int*   __restrict__ mask,  const float* __restrict__ scale,
    float* __restrict__ sparts)
{
    const int blk = blockIdx.x;
    const int b  = blk & 7;
    int r = blk >> 3;                 // 0..255
    const int dh = r & 1;
    r >>= 1;                          // 0..127
    const int sg = r & 31;
    const int tg = r >> 5;            // 0..3
    const int t0 = tg * 16, s0 = sg * 16;
    const int dbase = dh * 256;

    __shared__ float kT[16][132];
    __shared__ float qT[16][132];
    __shared__ float cS[128];

    const int tid  = threadIdx.x;
    const int t_l = tid >> 4;         // own t (0..15)
    const int s_l = tid & 15;         // own s (0..15)
    const int m = mask[b * S_ + s0 + s_l];

    const int lrow = tid >> 5;        // staging row 0..7 (and +8)
    const int lcol = (tid & 31) * 4;  // staging col (floats) 0..124

    float p0 = 0.f, p1 = 0.f;

    for (int c = 0; c < 2; ++c) {
        const int dc = dbase + c * 128;
        const float* kp = kproj + (size_t)(b * S_ + s0) * D_ + dc;
        const float* qp = qproj + (size_t)(b * T_ + t0) * D_ + dc;
        *(float4*)&kT[lrow][lcol]     = *(const float4*)(kp + (size_t)lrow * D_ + lcol);
        *(float4*)&kT[lrow + 8][lcol] = *(const float4*)(kp + (size_t)(lrow + 8) * D_ + lcol);
        *(float4*)&qT[lrow][lcol]     = *(const float4*)(qp + (size_t)lrow * D_ + lcol);
        *(float4*)&qT[lrow + 8][lcol] = *(const float4*)(qp + (size_t)(lrow + 8) * D_ + lcol);
        if (tid < 32) {
            *(float4*)&cS[tid * 4] = *(const float4*)(scale + dc + tid * 4);
        }
        __syncthreads();

#pragma unroll 4
        for (int j = 0; j < 32; ++j) {
            float4 k4 = *(const float4*)&kT[s_l][j * 4];
            float4 q4 = *(const float4*)&qT[t_l][j * 4];
            float4 c4 = *(const float4*)&cS[j * 4];
            float e0 = __builtin_amdgcn_exp2f(q4.x + k4.x);
            float e1 = __builtin_amdgcn_exp2f(q4.y + k4.y);
            float e2 = __builtin_amdgcn_exp2f(q4.z + k4.z);
            float e3 = __builtin_amdgcn_exp2f(q4.w + k4.w);
            float r0 = __builtin_amdgcn_rcpf(e0 + 1.0f);
            float r1 = __builtin_amdgcn_rcpf(e1 + 1.0f);
            float r2 = __builtin_amdgcn_rcpf(e2 + 1.0f);
            float r3 = __builtin_amdgcn_rcpf(e3 + 1.0f);
            p0 = fmaf(c4.x, r0, p0);
            p1 = fmaf(c4.y, r1, p1);
            p0 = fmaf(c4.z, r2, p0);
            p1 = fmaf(c4.w, r3, p1);
        }
        __syncthreads();
    }

    const float p = p0 + p1;
    const float out = m ? (-2.0f * p) : -5e8f;
    sparts[(size_t)dh * SN + (size_t)(b * T_ + t0 + t_l) * S_ + s0 + s_l] = out;
}

// ---------------------------------------------------------------------------
// Softmax + context (unchanged from R4 — passed twice). Grid 1024.
// ---------------------------------------------------------------------------
__global__ __launch_bounds__(256) void softmax_ctx(
    const float* __restrict__ sparts, const float* __restrict__ value,
    float* __restrict__ ctx, float* __restrict__ attn)
{
    const int blk = blockIdx.x;
    const int b = blk & 7;
    int r = blk >> 3;
    const int vc = r & 3;        // v-chunk of 128
    const int tp = r >> 2;       // 0..31
    const int t0 = tp * 2, t1 = t0 + 1;
    const size_t row0 = (size_t)(b * T_ + t0) * S_;
    const size_t row1 = row0 + S_;

    const int tid  = threadIdx.x;
    const int lane = tid & 63;
    const int wid  = tid >> 6;

    __shared__ float2 wp[S_];          // (w_t0, w_t1) per s
    __shared__ float4 part[2][8][32];  // [t][s-stream][v4]
    __shared__ float2 red2[8];

    const int sa = tid, sb = tid + 256;
    float2 xa, xb;
    xa.x = sparts[row0 + sa] + sparts[SN + row0 + sa];
    xa.y = sparts[row1 + sa] + sparts[SN + row1 + sa];
    xb.x = sparts[row0 + sb] + sparts[SN + row0 + sb];
    xb.y = sparts[row1 + sb] + sparts[SN + row1 + sb];

    float2 m2; m2.x = fmaxf(xa.x, xb.x); m2.y = fmaxf(xa.y, xb.y);
#pragma unroll
    for (int off = 32; off >= 1; off >>= 1) {
        m2.x = fmaxf(m2.x, __shfl_xor(m2.x, off));
        m2.y = fmaxf(m2.y, __shfl_xor(m2.y, off));
    }
    if (lane == 0) red2[wid] = m2;
    __syncthreads();
    {
        float2 r0 = red2[0], r1 = red2[1], r2 = red2[2], r3 = red2[3];
        m2.x = fmaxf(fmaxf(r0.x, r1.x), fmaxf(r2.x, r3.x));
        m2.y = fmaxf(fmaxf(r0.y, r1.y), fmaxf(r2.y, r3.y));
    }

    float2 ea, eb;
    ea.x = __builtin_amdgcn_exp2f((xa.x - m2.x) * LOG2E);
    ea.y = __builtin_amdgcn_exp2f((xa.y - m2.y) * LOG2E);
    eb.x = __builtin_amdgcn_exp2f((xb.x - m2.x) * LOG2E);
    eb.y = __builtin_amdgcn_exp2f((xb.y - m2.y) * LOG2E);

    float2 s2; s2.x = ea.x + eb.x; s2.y = ea.y + eb.y;
#pragma unroll
    for (int off = 32; off >= 1; off >>= 1) {
        s2.x += __shfl_xor(s2.x, off);
        s2.y += __shfl_xor(s2.y, off);
    }
    if (lane == 0) red2[4 + wid] = s2;
    __syncthreads();
    {
        float2 r0 = red2[4], r1 = red2[5], r2 = red2[6], r3 = red2[7];
        s2.x = (r0.x + r1.x) + (r2.x + r3.x);
        s2.y = (r0.y + r1.y) + (r2.y + r3.y);
    }
    const float inv0 = 1.0f / s2.x, inv1 = 1.0f / s2.y;

    float wa0 = ea.x * inv0, wb0 = eb.x * inv0;   // t0 at s=sa, sb
    float wa1 = ea.y * inv1, wb1 = eb.y * inv1;   // t1

    float2 wsa; wsa.x = wa0; wsa.y = wa1;
    float2 wsb; wsb.x = wb0; wsb.y = wb1;
    wp[sa] = wsa;
    wp[sb] = wsb;
    if (vc == 0) {
        attn[row0 + sa] = wa0; attn[row0 + sb] = wb0;
        attn[row1 + sa] = wa1; attn[row1 + sb] = wb1;
    }
    __syncthreads();

    // context: 8 s-streams (wid*2 + lane>>5), 32 v4-slots, float4 loads.
    const int ssub = wid * 2 + (lane >> 5);   // 0..7, owns s in [ssub*64, +64)
    const int v4   = lane & 31;
    const int v    = vc * 128 + v4 * 4;
    const float* vb = value + ((size_t)(b * S_) + ssub * 64) * D_ + v;
    float4 a0; a0.x = 0.f; a0.y = 0.f; a0.z = 0.f; a0.w = 0.f;
    float4 a1 = a0;
#pragma unroll 4
    for (int i = 0; i < 64; ++i) {
        float4 vv = *(const float4*)(vb + (size_t)i * D_);
        float2 w2 = wp[ssub * 64 + i];
        a0.x = fmaf(w2.x, vv.x, a0.x);
        a0.y = fmaf(w2.x, vv.y, a0.y);
        a0.z = fmaf(w2.x, vv.z, a0.z);
        a0.w = fmaf(w2.x, vv.w, a0.w);
        a1.x = fmaf(w2.y, vv.x, a1.x);
        a1.y = fmaf(w2.y, vv.y, a1.y);
        a1.z = fmaf(w2.y, vv.z, a1.z);
        a1.w = fmaf(w2.y, vv.w, a1.w);
    }
    part[0][ssub][v4] = a0;
    part[1][ssub][v4] = a1;
    __syncthreads();
    if (tid < 64) {
        const int ts = tid >> 5, w4 = tid & 31;
        float4 s0 = part[ts][0][w4], s1 = part[ts][1][w4];
        float4 s2v = part[ts][2][w4], s3 = part[ts][3][w4];
        float4 s4 = part[ts][4][w4], s5 = part[ts][5][w4];
        float4 s6 = part[ts][6][w4], s7 = part[ts][7][w4];
        float4 o;
        o.x = ((s0.x + s1.x) + (s2v.x + s3.x)) + ((s4.x + s5.x) + (s6.x + s7.x));
        o.y = ((s0.y + s1.y) + (s2v.y + s3.y)) + ((s4.y + s5.y) + (s6.y + s7.y));
        o.z = ((s0.z + s1.z) + (s2v.z + s3.z)) + ((s4.z + s5.z) + (s6.z + s7.z));
        o.w = ((s0.w + s1.w) + (s2v.w + s3.w)) + ((s4.w + s5.w) + (s6.w + s7.w));
        *(float4*)(ctx + (size_t)(b * T_ + t0 + ts) * D_ + vc * 128 + w4 * 4) = o;
    }
}

extern "C" void kernel_launch(void* const* d_in, const int* in_sizes, int n_in,
                              void* d_out, int out_size, void* d_ws, size_t ws_size,
                              hipStream_t stream) {
    const float* query = (const float*)d_in[0];
    const float* value = (const float*)d_in[1];
    const int*   mask  = (const int*)  d_in[2];
    const float* W1w   = (const float*)d_in[3];
    const float* W1b   = (const float*)d_in[4];
    const float* W2w   = (const float*)d_in[5];
    const float* W2b   = (const float*)d_in[6];
    const float* scale = (const float*)d_in[7];

    float* ctx  = (float*)d_out;
    float* attn = (float*)d_out + (size_t)B_ * T_ * D_;

    unsigned short* vb  = (unsigned short*)d_ws;        // 2M ushort (4 MB)
    unsigned short* qb  = vb + (size_t)KN;              // 256K
    unsigned short* w1t = qb + (size_t)QN;              // 256K
    unsigned short* w2t = w1t + (size_t)QN;             // 256K
    float* qproj = (float*)(w2t + (size_t)QN);          // QN f32 (1 MB)
    float* kproj = qproj + (size_t)QN;                  // KN f32 (8 MB)
    float* spart = kproj + (size_t)KN;                  // 2*SN f32 (2 MB)

    pack_bf16<<<1408, 256, 0, stream>>>(query, value, W1w, W2w, qb, vb, w1t, w2t);
    mfma_gemm<<<576, 256, 0, stream>>>(qb, vb, w1t, w2t, W1b, W2b, qproj, kproj);
    scores_t<<<2048, 256, 0, stream>>>(qproj, kproj, mask, scale, spart);
    softmax_ctx<<<1024, 256, 0, stream>>>(spart, value, ctx, attn);
}

// Round 6
// 131.780 us; speedup vs baseline: 1.3410x; 1.0275x over previous
//
#include <hip/hip_runtime.h>
#include <hip/hip_bf16.h>

// Dims fixed by setup_inputs(): b=8, t=64, s=512, qu=vu=d=512.
#define B_  8
#define T_  64
#define S_  512
#define D_  512

#define QN (512 * 512)      // qproj elements (B*T x D)
#define KN (4096 * 512)     // kproj elements (B*S x D)
#define SN (B_ * T_ * S_)   // scores elements

#define TLOG2E 2.8853900817779268f   // 2*log2(e)
#define LOG2E  1.4426950408889634f

typedef __attribute__((ext_vector_type(8))) short bf16x8;
typedef __attribute__((ext_vector_type(4))) float f32x4;

__device__ __forceinline__ unsigned short f2bf(float f) {
    unsigned int u = __float_as_uint(f);
    return (unsigned short)((u + 0x7FFFu + ((u >> 16) & 1u)) >> 16);  // RNE
}
__device__ __forceinline__ unsigned int pk2(float a, float b) {
    return (unsigned int)f2bf(a) | ((unsigned int)f2bf(b) << 16);
}

// ---------------------------------------------------------------------------
// bf16 MFMA projection GEMM with INLINE f32->bf16 packing (no pack kernel,
// no bf16 global buffers). A (query/value) staged f32->bf16 during LDS write;
// W tile transposed in-LDS: coalesced f32 row-pair loads -> pk2 -> b32
// scatter (Bs[n][k], k-pairs). Software-pipelined: next tile prefetched into
// regs between the post-write barrier and the MFMA block.
// Block = 64x64 tile, 4 waves, each wave 2x2 of 16x16x32 mfma.
//   blocks [0,512):   kproj = value @ W2.  XCD swizzle: xcd = x&7 owns
//                     tm in [xcd*8, xcd*8+8) for all tn -> per-XCD L2 keeps
//                     its 1 MB value slice + W2 stripes resident.
//                     tm = (x&7)*8 + ((x>>3)&7), tn = x>>6.
//   blocks [512,576): qproj = query @ W1.  r=x-512: tm=r>>3, tn=r&7.
// Epilogue: *TLOG2E; q-GEMM adds (b1+b2) first.  LDS rows padded to 40
// ushorts (80 B, 16B-aligned): frag b128 reads are 2-way max (free).
// ---------------------------------------------------------------------------
__global__ __launch_bounds__(256) void mfma_gemm(
    const float* __restrict__ query, const float* __restrict__ value,
    const float* __restrict__ W1, const float* __restrict__ W2,
    const float* __restrict__ b1, const float* __restrict__ b2,
    float* __restrict__ qproj, float* __restrict__ kproj)
{
    __shared__ __align__(16) unsigned short Ab[64][40];
    __shared__ __align__(16) unsigned short Bs[64][40];

    const int x = blockIdx.x;
    const float *A, *W;
    float* C;
    int tm, tn;
    bool isq;
    if (x < 512) {
        tm = (x & 7) * 8 + ((x >> 3) & 7);
        tn = x >> 6;
        A = value; W = W2; C = kproj; isq = false;
    } else {
        int r = x - 512;
        tm = r >> 3; tn = r & 7;
        A = query; W = W1; C = qproj; isq = true;
    }

    const int tid  = threadIdx.x;
    const int lane = tid & 63;
    const int wid  = tid >> 6;
    const int wm = (wid & 1) * 32, wn = (wid >> 1) * 32;
    const int fm = lane & 15, fq = lane >> 4;

    f32x4 acc00 = {0.f, 0.f, 0.f, 0.f};
    f32x4 acc01 = acc00, acc10 = acc00, acc11 = acc00;

    // A staging: ar row 0..63, ac col (f32) 0,8,16,24
    const int ar = tid >> 2;
    const int ac = (tid & 3) * 8;
    const float* Ag = A + (size_t)(tm * 64 + ar) * 512 + ac;
    // W staging: c0 = 4 cols, kp = even k-pair row
    const int c0 = (tid & 15) * 4;
    const int kp = (tid >> 4) * 2;
    const float* Wg = W + (size_t)kp * 512 + tn * 64 + c0;

    // prefetch k0 = 0
    float4 av0 = *(const float4*)(Ag);
    float4 av1 = *(const float4*)(Ag + 4);
    float4 wv0 = *(const float4*)(Wg);
    float4 wv1 = *(const float4*)(Wg + 512);

    for (int k0 = 0; k0 < 512; k0 += 32) {
        __syncthreads();   // prev iter's frag reads done
        {
            uint4 pa;
            pa.x = pk2(av0.x, av0.y); pa.y = pk2(av0.z, av0.w);
            pa.z = pk2(av1.x, av1.y); pa.w = pk2(av1.z, av1.w);
            *(uint4*)&Ab[ar][ac] = pa;
            // W^T scatter: Bs[c0+j][kp..kp+1]
            *(unsigned int*)&Bs[c0 + 0][kp] = pk2(wv0.x, wv1.x);
            *(unsigned int*)&Bs[c0 + 1][kp] = pk2(wv0.y, wv1.y);
            *(unsigned int*)&Bs[c0 + 2][kp] = pk2(wv0.z, wv1.z);
            *(unsigned int*)&Bs[c0 + 3][kp] = pk2(wv0.w, wv1.w);
        }
        __syncthreads();
        // prefetch next tile (wraps to 0 on last iter; values unused)
        const int kn = (k0 + 32) & 511;
        av0 = *(const float4*)(Ag + kn);
        av1 = *(const float4*)(Ag + kn + 4);
        wv0 = *(const float4*)(Wg + (size_t)kn * 512);
        wv1 = *(const float4*)(Wg + (size_t)kn * 512 + 512);

        bf16x8 a0  = *(const bf16x8*)&Ab[wm + fm][fq * 8];
        bf16x8 a1  = *(const bf16x8*)&Ab[wm + 16 + fm][fq * 8];
        bf16x8 b0  = *(const bf16x8*)&Bs[wn + fm][fq * 8];
        bf16x8 b1v = *(const bf16x8*)&Bs[wn + 16 + fm][fq * 8];
        acc00 = __builtin_amdgcn_mfma_f32_16x16x32_bf16(a0, b0,  acc00, 0, 0, 0);
        acc01 = __builtin_amdgcn_mfma_f32_16x16x32_bf16(a0, b1v, acc01, 0, 0, 0);
        acc10 = __builtin_amdgcn_mfma_f32_16x16x32_bf16(a1, b0,  acc10, 0, 0, 0);
        acc11 = __builtin_amdgcn_mfma_f32_16x16x32_bf16(a1, b1v, acc11, 0, 0, 0);
    }

    // C/D layout (m89-verified): col = lane&15, row = fq*4 + reg.
    const int n0 = tn * 64 + wn + fm;
    const int n1 = n0 + 16;
    float bias0 = 0.f, bias1 = 0.f;
    if (isq) {
        bias0 = b1[n0] + b2[n0];
        bias1 = b1[n1] + b2[n1];
    }
    const int m0 = tm * 64 + wm + fq * 4;
#pragma unroll
    for (int r = 0; r < 4; ++r) {
        C[(size_t)(m0 + r) * 512 + n0]      = (acc00[r] + bias0) * TLOG2E;
        C[(size_t)(m0 + r) * 512 + n1]      = (acc01[r] + bias1) * TLOG2E;
        C[(size_t)(m0 + 16 + r) * 512 + n0] = (acc10[r] + bias0) * TLOG2E;
        C[(size_t)(m0 + 16 + r) * 512 + n1] = (acc11[r] + bias1) * TLOG2E;
    }
}

// ---------------------------------------------------------------------------
// Transposed scores (unchanged from R5 — verified): thread owns one (t,s)
// over a d-half. Stored value = -2*sum_d c_d*rcp(exp2(q'+k')+1) (csum dropped;
// softmax shift-invariant). Masked: -5e8 per half. q',k' pre-scaled by
// 2log2e + bias-folded in GEMM. (256,4) caps VGPR at 128.
// Grid 2048: blk = ((((tg*32+sg)*2)+dh) << 3) | b.
// ---------------------------------------------------------------------------
__global__ __launch_bounds__(256, 4) void scores_t(
    const float* __restrict__ qproj, const float* __restrict__ kproj,
    const int*   __restrict__ mask,  const float* __restrict__ scale,
    float* __restrict__ sparts)
{
    const int blk = blockIdx.x;
    const int b  = blk & 7;
    int r = blk >> 3;                 // 0..255
    const int dh = r & 1;
    r >>= 1;                          // 0..127
    const int sg = r & 31;
    const int tg = r >> 5;            // 0..3
    const int t0 = tg * 16, s0 = sg * 16;
    const int dbase = dh * 256;

    __shared__ float kT[16][132];
    __shared__ float qT[16][132];
    __shared__ float cS[128];

    const int tid  = threadIdx.x;
    const int t_l = tid >> 4;         // own t (0..15)
    const int s_l = tid & 15;         // own s (0..15)
    const int m = mask[b * S_ + s0 + s_l];

    const int lrow = tid >> 5;        // staging row 0..7 (and +8)
    const int lcol = (tid & 31) * 4;  // staging col (floats) 0..124

    float p0 = 0.f, p1 = 0.f;

    for (int c = 0; c < 2; ++c) {
        const int dc = dbase + c * 128;
        const float* kp = kproj + (size_t)(b * S_ + s0) * D_ + dc;
        const float* qp = qproj + (size_t)(b * T_ + t0) * D_ + dc;
        *(float4*)&kT[lrow][lcol]     = *(const float4*)(kp + (size_t)lrow * D_ + lcol);
        *(float4*)&kT[lrow + 8][lcol] = *(const float4*)(kp + (size_t)(lrow + 8) * D_ + lcol);
        *(float4*)&qT[lrow][lcol]     = *(const float4*)(qp + (size_t)lrow * D_ + lcol);
        *(float4*)&qT[lrow + 8][lcol] = *(const float4*)(qp + (size_t)(lrow + 8) * D_ + lcol);
        if (tid < 32) {
            *(float4*)&cS[tid * 4] = *(const float4*)(scale + dc + tid * 4);
        }
        __syncthreads();

#pragma unroll 4
        for (int j = 0; j < 32; ++j) {
            float4 k4 = *(const float4*)&kT[s_l][j * 4];
            float4 q4 = *(const float4*)&qT[t_l][j * 4];
            float4 c4 = *(const float4*)&cS[j * 4];
            float e0 = __builtin_amdgcn_exp2f(q4.x + k4.x);
            float e1 = __builtin_amdgcn_exp2f(q4.y + k4.y);
            float e2 = __builtin_amdgcn_exp2f(q4.z + k4.z);
            float e3 = __builtin_amdgcn_exp2f(q4.w + k4.w);
            float r0 = __builtin_amdgcn_rcpf(e0 + 1.0f);
            float r1 = __builtin_amdgcn_rcpf(e1 + 1.0f);
            float r2 = __builtin_amdgcn_rcpf(e2 + 1.0f);
            float r3 = __builtin_amdgcn_rcpf(e3 + 1.0f);
            p0 = fmaf(c4.x, r0, p0);
            p1 = fmaf(c4.y, r1, p1);
            p0 = fmaf(c4.z, r2, p0);
            p1 = fmaf(c4.w, r3, p1);
        }
        __syncthreads();
    }

    const float p = p0 + p1;
    const float out = m ? (-2.0f * p) : -5e8f;
    sparts[(size_t)dh * SN + (size_t)(b * T_ + t0 + t_l) * S_ + s0 + s_l] = out;
}

// ---------------------------------------------------------------------------
// Softmax + context, t-QUAD per block (value reuse x4). Grid 512:
// blk = ((tq*4 + vc) << 3) | b  (b low bits = XCD pin; value[b] L2-resident).
// Softmax for 4 t rows packed in float4 lanes; weights in LDS as float4/s;
// context: 8 s-streams x 32 v4-slots, float4 value loads, 16 fma/iter/thread.
// ---------------------------------------------------------------------------
__global__ __launch_bounds__(256) void softmax_ctx(
    const float* __restrict__ sparts, const float* __restrict__ value,
    float* __restrict__ ctx, float* __restrict__ attn)
{
    const int blk = blockIdx.x;
    const int b = blk & 7;
    int r = blk >> 3;
    const int vc = r & 3;        // v-chunk of 128
    const int tq = r >> 2;       // 0..15
    const int t0 = tq * 4;
    const size_t rbase = (size_t)(b * T_ + t0) * S_;

    const int tid  = threadIdx.x;
    const int lane = tid & 63;
    const int wid  = tid >> 6;

    __shared__ float4 wp4[S_];         // weights for 4 t's per s
    __shared__ float4 part[4][8][32];  // [t][s-stream][v4]
    __shared__ float4 red4[8];

    const int sa = tid, sb = tid + 256;
    float4 xa, xb;
    xa.x = sparts[rbase + sa]          + sparts[SN + rbase + sa];
    xa.y = sparts[rbase + S_ + sa]     + sparts[SN + rbase + S_ + sa];
    xa.z = sparts[rbase + 2 * S_ + sa] + sparts[SN + rbase + 2 * S_ + sa];
    xa.w = sparts[rbase + 3 * S_ + sa] + sparts[SN + rbase + 3 * S_ + sa];
    xb.x = sparts[rbase + sb]          + sparts[SN + rbase + sb];
    xb.y = sparts[rbase + S_ + sb]     + sparts[SN + rbase + S_ + sb];
    xb.z = sparts[rbase + 2 * S_ + sb] + sparts[SN + rbase + 2 * S_ + sb];
    xb.w = sparts[rbase + 3 * S_ + sb] + sparts[SN + rbase + 3 * S_ + sb];

    float4 m4;
    m4.x = fmaxf(xa.x, xb.x); m4.y = fmaxf(xa.y, xb.y);
    m4.z = fmaxf(xa.z, xb.z); m4.w = fmaxf(xa.w, xb.w);
#pragma unroll
    for (int off = 32; off >= 1; off >>= 1) {
        m4.x = fmaxf(m4.x, __shfl_xor(m4.x, off));
        m4.y = fmaxf(m4.y, __shfl_xor(m4.y, off));
        m4.z = fmaxf(m4.z, __shfl_xor(m4.z, off));
        m4.w = fmaxf(m4.w, __shfl_xor(m4.w, off));
    }
    if (lane == 0) red4[wid] = m4;
    __syncthreads();
    {
        float4 r0 = red4[0], r1 = red4[1], r2 = red4[2], r3 = red4[3];
        m4.x = fmaxf(fmaxf(r0.x, r1.x), fmaxf(r2.x, r3.x));
        m4.y = fmaxf(fmaxf(r0.y, r1.y), fmaxf(r2.y, r3.y));
        m4.z = fmaxf(fmaxf(r0.z, r1.z), fmaxf(r2.z, r3.z));
        m4.w = fmaxf(fmaxf(r0.w, r1.w), fmaxf(r2.w, r3.w));
    }

    float4 ea, eb;
    ea.x = __builtin_amdgcn_exp2f((xa.x - m4.x) * LOG2E);
    ea.y = __builtin_amdgcn_exp2f((xa.y - m4.y) * LOG2E);
    ea.z = __builtin_amdgcn_exp2f((xa.z - m4.z) * LOG2E);
    ea.w = __builtin_amdgcn_exp2f((xa.w - m4.w) * LOG2E);
    eb.x = __builtin_amdgcn_exp2f((xb.x - m4.x) * LOG2E);
    eb.y = __builtin_amdgcn_exp2f((xb.y - m4.y) * LOG2E);
    eb.z = __builtin_amdgcn_exp2f((xb.z - m4.z) * LOG2E);
    eb.w = __builtin_amdgcn_exp2f((xb.w - m4.w) * LOG2E);

    float4 s4;
    s4.x = ea.x + eb.x; s4.y = ea.y + eb.y;
    s4.z = ea.z + eb.z; s4.w = ea.w + eb.w;
#pragma unroll
    for (int off = 32; off >= 1; off >>= 1) {
        s4.x += __shfl_xor(s4.x, off);
        s4.y += __shfl_xor(s4.y, off);
        s4.z += __shfl_xor(s4.z, off);
        s4.w += __shfl_xor(s4.w, off);
    }
    if (lane == 0) red4[4 + wid] = s4;
    __syncthreads();
    {
        float4 r0 = red4[4], r1 = red4[5], r2 = red4[6], r3 = red4[7];
        s4.x = (r0.x + r1.x) + (r2.x + r3.x);
        s4.y = (r0.y + r1.y) + (r2.y + r3.y);
        s4.z = (r0.z + r1.z) + (r2.z + r3.z);
        s4.w = (r0.w + r1.w) + (r2.w + r3.w);
    }
    float4 inv4;
    inv4.x = 1.0f / s4.x; inv4.y = 1.0f / s4.y;
    inv4.z = 1.0f / s4.z; inv4.w = 1.0f / s4.w;

    float4 wa, wb;
    wa.x = ea.x * inv4.x; wa.y = ea.y * inv4.y;
    wa.z = ea.z * inv4.z; wa.w = ea.w * inv4.w;
    wb.x = eb.x * inv4.x; wb.y = eb.y * inv4.y;
    wb.z = eb.z * inv4.z; wb.w = eb.w * inv4.w;

    wp4[sa] = wa;
    wp4[sb] = wb;
    if (vc == 0) {
        attn[rbase + sa]          = wa.x; attn[rbase + sb]          = wb.x;
        attn[rbase + S_ + sa]     = wa.y; attn[rbase + S_ + sb]     = wb.y;
        attn[rbase + 2 * S_ + sa] = wa.z; attn[rbase + 2 * S_ + sb] = wb.z;
        attn[rbase + 3 * S_ + sa] = wa.w; attn[rbase + 3 * S_ + sb] = wb.w;
    }
    __syncthreads();

    // context: 8 s-streams (wid*2 + lane>>5), 32 v4-slots, float4 loads.
    const int ssub = wid * 2 + (lane >> 5);   // 0..7, owns s in [ssub*64, +64)
    const int v4   = lane & 31;
    const int v    = vc * 128 + v4 * 4;
    const float* vb = value + ((size_t)(b * S_) + ssub * 64) * D_ + v;
    float4 a0; a0.x = 0.f; a0.y = 0.f; a0.z = 0.f; a0.w = 0.f;
    float4 a1 = a0, a2 = a0, a3 = a0;
#pragma unroll 4
    for (int i = 0; i < 64; ++i) {
        float4 vv = *(const float4*)(vb + (size_t)i * D_);
        float4 w4 = wp4[ssub * 64 + i];
        a0.x = fmaf(w4.x, vv.x, a0.x); a0.y = fmaf(w4.x, vv.y, a0.y);
        a0.z = fmaf(w4.x, vv.z, a0.z); a0.w = fmaf(w4.x, vv.w, a0.w);
        a1.x = fmaf(w4.y, vv.x, a1.x); a1.y = fmaf(w4.y, vv.y, a1.y);
        a1.z = fmaf(w4.y, vv.z, a1.z); a1.w = fmaf(w4.y, vv.w, a1.w);
        a2.x = fmaf(w4.z, vv.x, a2.x); a2.y = fmaf(w4.z, vv.y, a2.y);
        a2.z = fmaf(w4.z, vv.z, a2.z); a2.w = fmaf(w4.z, vv.w, a2.w);
        a3.x = fmaf(w4.w, vv.x, a3.x); a3.y = fmaf(w4.w, vv.y, a3.y);
        a3.z = fmaf(w4.w, vv.z, a3.z); a3.w = fmaf(w4.w, vv.w, a3.w);
    }
    part[0][ssub][v4] = a0;
    part[1][ssub][v4] = a1;
    part[2][ssub][v4] = a2;
    part[3][ssub][v4] = a3;
    __syncthreads();
    if (tid < 128) {
        const int ts = tid >> 5, w4i = tid & 31;
        float4 p0 = part[ts][0][w4i], p1 = part[ts][1][w4i];
        float4 p2 = part[ts][2][w4i], p3 = part[ts][3][w4i];
        float4 p4 = part[ts][4][w4i], p5 = part[ts][5][w4i];
        float4 p6 = part[ts][6][w4i], p7 = part[ts][7][w4i];
        float4 o;
        o.x = ((p0.x + p1.x) + (p2.x + p3.x)) + ((p4.x + p5.x) + (p6.x + p7.x));
        o.y = ((p0.y + p1.y) + (p2.y + p3.y)) + ((p4.y + p5.y) + (p6.y + p7.y));
        o.z = ((p0.z + p1.z) + (p2.z + p3.z)) + ((p4.z + p5.z) + (p6.z + p7.z));
        o.w = ((p0.w + p1.w) + (p2.w + p3.w)) + ((p4.w + p5.w) + (p6.w + p7.w));
        *(float4*)(ctx + (size_t)(b * T_ + t0 + ts) * D_ + vc * 128 + w4i * 4) = o;
    }
}

extern "C" void kernel_launch(void* const* d_in, const int* in_sizes, int n_in,
                              void* d_out, int out_size, void* d_ws, size_t ws_size,
                              hipStream_t stream) {
    const float* query = (const float*)d_in[0];
    const float* value = (const float*)d_in[1];
    const int*   mask  = (const int*)  d_in[2];
    const float* W1w   = (const float*)d_in[3];
    const float* W1b   = (const float*)d_in[4];
    const float* W2w   = (const float*)d_in[5];
    const float* W2b   = (const float*)d_in[6];
    const float* scale = (const float*)d_in[7];

    float* ctx  = (float*)d_out;
    float* attn = (float*)d_out + (size_t)B_ * T_ * D_;

    float* qproj = (float*)d_ws;              // QN f32 (1 MB)
    float* kproj = qproj + (size_t)QN;        // KN f32 (8 MB)
    float* spart = kproj + (size_t)KN;        // 2*SN f32 (2 MB)

    mfma_gemm<<<576, 256, 0, stream>>>(query, value, W1w, W2w, W1b, W2b,
                                       qproj, kproj);
    scores_t<<<2048, 256, 0, stream>>>(qproj, kproj, mask, scale, spart);
    softmax_ctx<<<512, 256, 0, stream>>>(spart, value, ctx, attn);
}